// Round 5
// baseline (95.129 us; speedup 1.0000x reference)
//
#include <hip/hip_runtime.h>
#include <utility>
#include <math.h>

// Problem constants (fixed by the reference)
#define BATCH     128
#define IN_DIM    784
#define HIDDEN    100
#define MM        10      // M_MODES
#define NPH       5       // N_PHOT
#define NSTATES   2002    // C(14,5)
#define NCLASSES  10

// ---------------------------------------------------------------------------
// Compile-time state table: all C(14,5)=2002 multisets of 5 modes from 10,
// lexicographic (matches itertools.combinations_with_replacement). Packed:
// bits [0:20)  = 5 x 4-bit mode digits (non-decreasing)
// bits [20:27) = fact = prod(factorial(multiplicity))  (max 5! = 120)
// ---------------------------------------------------------------------------
struct StateTbl { unsigned v[NSTATES]; };

constexpr StateTbl make_state_tbl() {
    StateTbl t{};
    int idx = 0;
    for (int a = 0; a < MM; ++a)
    for (int b = a; b < MM; ++b)
    for (int c = b; c < MM; ++c)
    for (int d = c; d < MM; ++d)
    for (int e = d; e < MM; ++e) {
        int cnt[MM] = {};
        cnt[a]++; cnt[b]++; cnt[c]++; cnt[d]++; cnt[e]++;
        int f = 1;
        for (int m = 0; m < MM; ++m) {
            int kf = 1;
            for (int i = 2; i <= cnt[m]; ++i) kf *= i;
            f *= kf;
        }
        t.v[idx++] = (unsigned)a | ((unsigned)b << 4) | ((unsigned)c << 8) |
                     ((unsigned)d << 12) | ((unsigned)e << 16) |
                     ((unsigned)f << 20);
    }
    return t;
}

__device__ const StateTbl STATE_TBL = make_state_tbl();

// ---------------------------------------------------------------------------
// Glynn formula, Gray-coded over delta_1..delta_4 (delta_0 fixed +1):
//   perm(A) = 2^{-4} * sum_{delta} (prod_k delta_k) * prod_j (sum_i delta_i A[i][j])
// 16 terms. Fully template-unrolled: row index, sign, and +-2 coefficient are
// all constexpr -> pure VGPR arithmetic (needs ~72 live VGPRs -> fits the
// 128-VGPR cap of a 1024-thread block; R4's default heuristic capped at 72
// and spilled, costing ~40 us).
// ---------------------------------------------------------------------------
template <int K>   // flip from state K-1 to K, K in [1,16)
__device__ __forceinline__ void glynn_step(
    const float (&mr)[5][5], const float (&mi)[5][5],
    float (&cr)[5], float (&ci)[5], float& accr, float& acci)
{
    constexpr int   bit  = (K & 1) ? 0 : ((K & 2) ? 1 : ((K & 4) ? 2 : 3));
    constexpr int   gray = K ^ (K >> 1);
    constexpr int   row  = bit + 1;                       // delta_row flips
    constexpr float s2   = ((gray >> bit) & 1) ? -2.0f : 2.0f;
    constexpr int   pc   = (gray & 1) + ((gray >> 1) & 1) +
                           ((gray >> 2) & 1) + ((gray >> 3) & 1);
    #pragma unroll
    for (int j = 0; j < 5; ++j) {
        cr[j] = fmaf(s2, mr[row][j], cr[j]);
        ci[j] = fmaf(s2, mi[row][j], ci[j]);
    }
    float pr = cr[0], pi = ci[0];
    #pragma unroll
    for (int j = 1; j < 5; ++j) {
        const float nr = pr * cr[j] - pi * ci[j];
        const float ni = pr * ci[j] + pi * cr[j];
        pr = nr; pi = ni;
    }
    if constexpr ((pc & 1) != 0) { accr -= pr; acci -= pi; }
    else                         { accr += pr; acci += pi; }
}

template <int... Ks>
__device__ __forceinline__ void glynn_run(
    std::integer_sequence<int, Ks...>,
    const float (&mr)[5][5], const float (&mi)[5][5],
    float (&cr)[5], float (&ci)[5], float& accr, float& acci)
{
    (glynn_step<Ks + 1>(mr, mi, cr, ci, accr, acci), ...);
}

// ---------------------------------------------------------------------------
// Fused kernel: one block per batch row (128 blocks x 1024 threads).
// Phase 1: A[b] (10x5 complex) in LDS from x,W1,b1,WL,WR.
// Phase 2: 2 states/thread -> Glynn permanent -> probs[2048] in LDS
//          (no per-thread cls[] accumulators -> low VGPR pressure).
// Phase 3: wave c (c<10) reduces probs . W2[c] (coalesced), direct store.
// ---------------------------------------------------------------------------
__global__ __launch_bounds__(1024) void qc_fused(
    const float* __restrict__ x, const float* __restrict__ W1,
    const float* __restrict__ b1,
    const float* __restrict__ wl_re, const float* __restrict__ wl_im,
    const float* __restrict__ wr_re, const float* __restrict__ wr_im,
    const float* __restrict__ W2, const float* __restrict__ b2,
    float* __restrict__ out)
{
    __shared__ __align__(16) float xs[IN_DIM];
    __shared__ float  part[800];
    __shared__ float  hs[HIDDEN];
    __shared__ float  phc[MM], phs_[MM];
    __shared__ float  plr[50], pli[50];
    __shared__ float2 a2[50];
    __shared__ float  probs[2048];

    const int b   = blockIdx.x;
    const int tid = threadIdx.x;

    // ---- Phase 1: A[b] ----
    if (tid < IN_DIM) xs[tid] = x[b * IN_DIM + tid];
    __syncthreads();

    // GEMM: 8 threads per hidden row, 98 elems each (float2 x 49)
    if (tid < 800) {
        const int j = tid >> 3, q = tid & 7;
        const float* wrow = W1 + j * IN_DIM + q * 98;
        const float* xr   = xs + q * 98;
        float2 acc = make_float2(0.f, 0.f);
        #pragma unroll 7
        for (int i = 0; i < 98; i += 2) {
            const float2 w  = *(const float2*)(wrow + i);
            const float2 xv = *(const float2*)(xr + i);
            acc.x += w.x * xv.x; acc.y += w.y * xv.y;
        }
        part[tid] = acc.x + acc.y;
    }
    __syncthreads();

    if (tid < HIDDEN) {
        const float* p = part + 8 * tid;
        float t = ((p[0] + p[1]) + (p[2] + p[3])) +
                  ((p[4] + p[5]) + (p[6] + p[7])) + b1[tid];
        hs[tid] = 1.0f / (1.0f + expf(-t));
    }
    __syncthreads();

    if (tid < MM) {
        float th = 0.f;
        #pragma unroll
        for (int g = 0; g < MM; ++g) th += hs[g * MM + tid];
        float sv, cv;
        sincosf(th, &sv, &cv);
        phc[tid] = cv; phs_[tid] = sv;
    }
    __syncthreads();

    if (tid < 50) {   // PL[q][c] = phase[q] * WL[q][2c]
        const int q = tid / 5, c = tid % 5;
        const float lr = wl_re[q * MM + 2 * c], li = wl_im[q * MM + 2 * c];
        plr[tid] = phc[q] * lr - phs_[q] * li;
        pli[tid] = phc[q] * li + phs_[q] * lr;
    }
    __syncthreads();

    if (tid < 50) {   // A[p][c] = sum_q WR[p][q] * PL[q][c]
        const int p = tid / 5, c = tid % 5;
        float ar = 0.f, ai = 0.f;
        #pragma unroll
        for (int q = 0; q < MM; ++q) {
            const float rr = wr_re[p * MM + q], ri = wr_im[p * MM + q];
            const float br = plr[q * 5 + c],    bi = pli[q * 5 + c];
            ar += rr * br - ri * bi;
            ai += rr * bi + ri * br;
        }
        a2[tid] = make_float2(ar, ai);
    }
    __syncthreads();

    // ---- Phase 2: permanents -> probs[] in LDS ----
    #pragma unroll
    for (int t = 0; t < 2; ++t) {
        const int s = (t << 10) + tid;
        if (s < NSTATES) {
            const unsigned w = STATE_TBL.v[s];   // coalesced dword load

            // gather 5x5 complex submatrix into registers (rows = state modes)
            float mr[5][5], mi[5][5];
            #pragma unroll
            for (int n = 0; n < 5; ++n) {
                const int base = ((w >> (4 * n)) & 15) * 5;
                #pragma unroll
                for (int j = 0; j < 5; ++j) {
                    const float2 e = a2[base + j];
                    mr[n][j] = e.x; mi[n][j] = e.y;
                }
            }

            // init: all deltas +1 -> colsums = sum of rows, first term +prod
            float cr[5], ci[5];
            #pragma unroll
            for (int j = 0; j < 5; ++j) {
                cr[j] = ((mr[0][j] + mr[1][j]) + (mr[2][j] + mr[3][j])) + mr[4][j];
                ci[j] = ((mi[0][j] + mi[1][j]) + (mi[2][j] + mi[3][j])) + mi[4][j];
            }
            float accr, acci;
            {
                float pr = cr[0], pi = ci[0];
                #pragma unroll
                for (int j = 1; j < 5; ++j) {
                    const float nr = pr * cr[j] - pi * ci[j];
                    const float ni = pr * ci[j] + pi * cr[j];
                    pr = nr; pi = ni;
                }
                accr = pr; acci = pi;
            }
            glynn_run(std::make_integer_sequence<int, 15>{}, mr, mi, cr, ci, accr, acci);

            // perm = acc/16  ->  |perm|^2 = (accr^2+acci^2)/256
            const float fact = (float)(w >> 20);
            probs[s] = (accr * accr + acci * acci) / (256.0f * fact);
        } else {
            probs[s] = 0.f;   // pad slots 2002..2047
        }
    }
    __syncthreads();

    // ---- Phase 3: wave c computes out[b][c] = probs . W2[c] + b2[c] ----
    const int c    = tid >> 6;     // wave index, classes 0..9 active
    const int lane = tid & 63;
    if (c < NCLASSES) {
        const float* w2row = W2 + c * NSTATES;
        float v = 0.f;
        for (int s = lane; s < NSTATES; s += 64)
            v = fmaf(probs[s], w2row[s], v);
        #pragma unroll
        for (int off = 32; off > 0; off >>= 1) v += __shfl_down(v, off, 64);
        if (lane == 0) out[b * NCLASSES + c] = v + b2[c];
    }
}

// ---------------------------------------------------------------------------
extern "C" void kernel_launch(void* const* d_in, const int* in_sizes, int n_in,
                              void* d_out, int out_size, void* d_ws, size_t ws_size,
                              hipStream_t stream)
{
    const float* x     = (const float*)d_in[0];
    const float* W1    = (const float*)d_in[1];
    const float* b1    = (const float*)d_in[2];
    const float* wl_re = (const float*)d_in[3];
    const float* wl_im = (const float*)d_in[4];
    const float* wr_re = (const float*)d_in[5];
    const float* wr_im = (const float*)d_in[6];
    const float* W2    = (const float*)d_in[7];
    const float* b2    = (const float*)d_in[8];
    float*       out   = (float*)d_out;

    qc_fused<<<BATCH, 1024, 0, stream>>>(x, W1, b1, wl_re, wl_im,
                                         wr_re, wr_im, W2, b2, out);
}